// Round 10
// baseline (291.610 us; speedup 1.0000x reference)
//
#include <hip/hip_runtime.h>
#include <hip/hip_bf16.h>

// B=32, Cin=96, HW=3136 (56x56), planes=576, Cout=96. hw tiles: 49 x 64 (exact).
#define BATCH 32
#define CIN 96
#define HW 3136
#define PL 576
#define COUT 96
#define NT 49
#define NHW 100352.0

typedef __attribute__((ext_vector_type(4))) float f32x4;
typedef __attribute__((ext_vector_type(8))) short s16x8;

__device__ __forceinline__ unsigned short f2b(float v) {
  __hip_bfloat16 h = __float2bfloat16(v);
  return *reinterpret_cast<unsigned short*>(&h);
}
__device__ __forceinline__ float b2f(unsigned int u) {
  return __uint_as_float((u & 0xffffu) << 16);
}

// ---------------- ternarize, parallel: stage 1 = partial |w| sums ---------------
__global__ __launch_bounds__(256) void absred_kernel(const float* __restrict__ w,
                                                     float* __restrict__ part, int n4) {
  __shared__ float ra[256];
  const int tid = threadIdx.x;
  float s = 0.f;
  for (int i = blockIdx.x * 256 + tid; i < n4; i += 32 * 256) {
    float4 v = reinterpret_cast<const float4*>(w)[i];
    s += fabsf(v.x) + fabsf(v.y) + fabsf(v.z) + fabsf(v.w);
  }
  ra[tid] = s; __syncthreads();
  for (int off = 128; off; off >>= 1) { if (tid < off) ra[tid] += ra[tid + off]; __syncthreads(); }
  if (tid == 0) part[blockIdx.x] = ra[0];
}

__device__ __forceinline__ float delta_from_parts(const float* __restrict__ part, float invn) {
  float s = 0.f;
#pragma unroll
  for (int i = 0; i < 32; ++i) s += part[i];
  return 0.7f * s * invn;
}

__global__ __launch_bounds__(256) void ternw_bf16_kernel(
    const float* __restrict__ w, const float* __restrict__ part, float invn,
    __hip_bfloat16* __restrict__ tw, int n4) {
  const float delta = delta_from_parts(part, invn);
  const int i = blockIdx.x * 256 + threadIdx.x;
  if (i >= n4) return;
  float4 v = reinterpret_cast<const float4*>(w)[i];
  float vv[4] = {v.x, v.y, v.z, v.w};
  unsigned short b[4];
#pragma unroll
  for (int j = 0; j < 4; ++j)
    b[j] = (fabsf(vv[j]) > delta)
               ? (unsigned short)(0x3F80u | ((__float_as_uint(vv[j]) >> 16) & 0x8000u))
               : (unsigned short)0;
  unsigned lo = (unsigned)b[0] | ((unsigned)b[1] << 16);
  unsigned hi = (unsigned)b[2] | ((unsigned)b[3] << 16);
  reinterpret_cast<uint2*>(tw)[i] = make_uint2(lo, hi);
}

__global__ __launch_bounds__(256) void ternw_f32_kernel(
    const float* __restrict__ w, const float* __restrict__ part, float invn,
    float* __restrict__ tw, int n4) {
  const float delta = delta_from_parts(part, invn);
  const int i = blockIdx.x * 256 + threadIdx.x;
  if (i >= n4) return;
  float4 v = reinterpret_cast<const float4*>(w)[i];
  float4 o;
  o.x = (fabsf(v.x) > delta) ? (v.x > 0.f ? 1.f : -1.f) : 0.f;
  o.y = (fabsf(v.y) > delta) ? (v.y > 0.f ? 1.f : -1.f) : 0.f;
  o.z = (fabsf(v.z) > delta) ? (v.z > 0.f ? 1.f : -1.f) : 0.f;
  o.w = (fabsf(v.w) > delta) ? (v.w > 0.f ? 1.f : -1.f) : 0.f;
  reinterpret_cast<float4*>(tw)[i] = o;
}

// ---------------- BN param: sc = g*inv, sh = b - mean*g*inv ---------------------
__global__ __launch_bounds__(256) void bnp_kernel(
    const float* __restrict__ psum, const float* __restrict__ psumsq,
    const float* __restrict__ gamma, const float* __restrict__ beta,
    float* __restrict__ sc, float* __restrict__ sh, int nparts) {
  const int ch = blockIdx.x, tid = threadIdx.x;
  double s = 0.0, q = 0.0;
  for (int i = tid; i < nparts; i += 256) {
    s += (double)psum[(size_t)ch * nparts + i];
    q += (double)psumsq[(size_t)ch * nparts + i];
  }
  __shared__ double rs[256], rq[256];
  rs[tid] = s; rq[tid] = q; __syncthreads();
  for (int off = 128; off; off >>= 1) {
    if (tid < off) { rs[tid] += rs[tid + off]; rq[tid] += rq[tid + off]; }
    __syncthreads();
  }
  if (tid == 0) {
    double mean = rs[0] / NHW;
    double var = rq[0] / NHW - mean * mean;
    float inv = (float)(1.0 / sqrt(var + 1e-5));
    float g = gamma[ch];
    sc[ch] = inv * g;
    sh[ch] = beta[ch] - (float)mean * inv * g;
  }
}

// ---------------- xcast: x [n][c][hw] f32 -> xb [n][hw][96] bf16 ----------------
// grid (49, 32). LDS-tiled transpose; coalesced both sides.
__global__ __launch_bounds__(256) void xcast_kernel(const float* __restrict__ x,
                                                    __hip_bfloat16* __restrict__ xb) {
  __shared__ __hip_bfloat16 Bt[64 * 104];
  const int hwt = blockIdx.x, n = blockIdx.y;
  const int t0 = hwt * 64, tid = threadIdx.x;
  const int lane = tid & 63, w = tid >> 6;
  {
    const float* xp = x + (size_t)n * CIN * HW + t0 + lane;
    const int cb = w * 24;
#pragma unroll
    for (int i6 = 0; i6 < 6; ++i6) {
      const int c0 = cb + i6 * 4;
      float v0 = xp[(size_t)(c0 + 0) * HW];
      float v1 = xp[(size_t)(c0 + 1) * HW];
      float v2 = xp[(size_t)(c0 + 2) * HW];
      float v3 = xp[(size_t)(c0 + 3) * HW];
      unsigned lo = (unsigned)f2b(v0) | ((unsigned)f2b(v1) << 16);
      unsigned hi = (unsigned)f2b(v2) | ((unsigned)f2b(v3) << 16);
      *reinterpret_cast<uint2*>(&Bt[lane * 104 + c0]) = make_uint2(lo, hi);
    }
  }
  __syncthreads();
  for (int i = tid; i < 768; i += 256) {   // 64 hw x 12 octs
    const int hw = i / 12, oct = i - hw * 12;
    uint4 v = *reinterpret_cast<const uint4*>(&Bt[hw * 104 + oct * 8]);
    *reinterpret_cast<uint4*>(xb + ((size_t)(n * HW + t0 + hw)) * 96 + oct * 8) = v;
  }
}

// ---------------- conv1 stats-only: BN1 partials, no output stored --------------
// grid (49, 32, 3), block 256. Identical numerics to the former conv1 partials.
__global__ __launch_bounds__(256) void conv1_stats(
    const float* __restrict__ x, const __hip_bfloat16* __restrict__ tw1,
    float* __restrict__ psum, float* __restrict__ psumsq) {
  __shared__ __hip_bfloat16 Bt[64 * 104];
  const int hwt = blockIdx.x, n = blockIdx.y, mt = blockIdx.z;
  const int t0 = hwt * 64, tid = threadIdx.x;
  const int lane = tid & 63, w = tid >> 6;
  {
    const float* xp = x + (size_t)n * CIN * HW + t0 + lane;
    const int cb = w * 24;
#pragma unroll
    for (int i6 = 0; i6 < 6; ++i6) {
      const int c0 = cb + i6 * 4;
      float v0 = xp[(size_t)(c0 + 0) * HW];
      float v1 = xp[(size_t)(c0 + 1) * HW];
      float v2 = xp[(size_t)(c0 + 2) * HW];
      float v3 = xp[(size_t)(c0 + 3) * HW];
      unsigned lo = (unsigned)f2b(v0) | ((unsigned)f2b(v1) << 16);
      unsigned hi = (unsigned)f2b(v2) | ((unsigned)f2b(v3) << 16);
      *reinterpret_cast<uint2*>(&Bt[lane * 104 + c0]) = make_uint2(lo, hi);
    }
  }
  __syncthreads();
  const int l15 = lane & 15, lh = lane >> 4;
  f32x4 acc[3][4];
#pragma unroll
  for (int f = 0; f < 3; ++f)
#pragma unroll
    for (int g = 0; g < 4; ++g) acc[f][g] = (f32x4){0.f, 0.f, 0.f, 0.f};
  const int rowb = mt * 192 + w * 48;
#pragma unroll
  for (int k0 = 0; k0 < 3; ++k0) {
    s16x8 a[3], b[4];
#pragma unroll
    for (int f = 0; f < 3; ++f)
      a[f] = *reinterpret_cast<const s16x8*>(tw1 + (size_t)(rowb + f * 16 + l15) * CIN + k0 * 32 + lh * 8);
#pragma unroll
    for (int g = 0; g < 4; ++g)
      b[g] = *reinterpret_cast<const s16x8*>(&Bt[(g * 16 + l15) * 104 + k0 * 32 + lh * 8]);
#pragma unroll
    for (int f = 0; f < 3; ++f)
#pragma unroll
      for (int g = 0; g < 4; ++g)
        acc[f][g] = __builtin_amdgcn_mfma_f32_16x16x32_bf16(a[f], b[g], acc[f][g], 0, 0, 0);
  }
#pragma unroll
  for (int f = 0; f < 3; ++f) {
    float sred[4] = {0.f, 0.f, 0.f, 0.f};
    float qred[4] = {0.f, 0.f, 0.f, 0.f};
    const int ch0 = rowb + f * 16 + lh * 4;
#pragma unroll
    for (int g = 0; g < 4; ++g)
#pragma unroll
      for (int r = 0; r < 4; ++r) {
        float v = acc[f][g][r];
        sred[r] += v; qred[r] = fmaf(v, v, qred[r]);
      }
#pragma unroll
    for (int r = 0; r < 4; ++r) {
      float s = sred[r], q = qred[r];
#pragma unroll
      for (int m = 1; m < 16; m <<= 1) { s += __shfl_xor(s, m); q += __shfl_xor(q, m); }
      if (l15 == 0) {
        const int pi = (ch0 + r) * 1568 + n * NT + hwt;
        psum[pi] = s; psumsq[pi] = q;
      }
    }
  }
}

// ---------------- fused conv1+BN1+ReLU+dw(+BN2 partials) -> o2c -----------------
// grid (49 tiles 8x8, 32 batch), block 256 (4 waves). kc loop (9 x 64 couts).
// Halo 10x10 positions staged from xb; conv1 via MFMA (M=64,N=112pad,K=96);
// dw per (pos, 4ch) unit from LDS; o2c stores 128B-coalesced.
__global__ __launch_bounds__(256) void fused_kernel(
    const __hip_bfloat16* __restrict__ xb, const __hip_bfloat16* __restrict__ tw1,
    const float* __restrict__ tw2, const float* __restrict__ s1,
    const float* __restrict__ t1, __hip_bfloat16* __restrict__ o2c,
    float* __restrict__ psum, float* __restrict__ psumsq) {
  __shared__ __hip_bfloat16 Bts[112 * 104];   // 23.3 KB halo x-tile [pos][c]
  __shared__ __hip_bfloat16 ot[100 * 76];     // 15.2 KB conv1-out [pos][ch64]
  __shared__ float wsh[9 * 64];               // dw weights [tap][ch]
  __shared__ float red0[4 * 64], red1[4 * 64];
  const int tb = blockIdx.x, n = blockIdx.y;
  const int tr0 = (tb / 7) * 8, tc0 = (tb - (tb / 7) * 7) * 8;
  const int tid = threadIdx.x;
  const int lane = tid & 63, wm = tid >> 6;
  const int l15 = lane & 15, lh = lane >> 4;

  // stage halo: 112 pos x 12 octs (pos>=100 zero)
  for (int i = tid; i < 1344; i += 256) {
    const int pos = i / 12, oct = i - pos * 12;
    uint4 v = make_uint4(0u, 0u, 0u, 0u);
    if (pos < 100) {
      const int hr = pos / 10, hc = pos - hr * 10;
      const int r = tr0 + hr - 1, c = tc0 + hc - 1;
      if ((unsigned)r < 56u && (unsigned)c < 56u)
        v = *reinterpret_cast<const uint4*>(xb + (size_t)(n * HW + r * 56 + c) * 96 + oct * 8);
    }
    *reinterpret_cast<uint4*>(&Bts[pos * 104 + oct * 8]) = v;
  }
  __syncthreads();

  const int q4 = tid & 15, pgrp = tid >> 4;

  for (int kc = 0; kc < 9; ++kc) {
    // stage dw weights for this chunk: tw2 linear [ch*9+tap]
    for (int i = tid; i < 576; i += 256) {
      const int chl = i / 9, tap = i - chl * 9;
      wsh[tap * 64 + chl] = tw2[kc * 576 + i];
    }
    // conv1 MFMA: wave wm owns couts kc*64 + wm*16 + [0,16)
    f32x4 acc[7];
#pragma unroll
    for (int g = 0; g < 7; ++g) acc[g] = (f32x4){0.f, 0.f, 0.f, 0.f};
    const int rowc = kc * 64 + wm * 16;
#pragma unroll
    for (int k0 = 0; k0 < 3; ++k0) {
      const s16x8 a = *reinterpret_cast<const s16x8*>(
          tw1 + (size_t)(rowc + l15) * CIN + k0 * 32 + lh * 8);
#pragma unroll
      for (int g = 0; g < 7; ++g) {
        const s16x8 b = *reinterpret_cast<const s16x8*>(
            &Bts[(g * 16 + l15) * 104 + k0 * 32 + lh * 8]);
        acc[g] = __builtin_amdgcn_mfma_f32_16x16x32_bf16(a, b, acc[g], 0, 0, 0);
      }
    }
    // BN1 + ReLU -> ot (invalid/out-of-image positions -> zeros)
    float scv[4], shv[4];
#pragma unroll
    for (int r = 0; r < 4; ++r) {
      const int ch = rowc + lh * 4 + r;
      scv[r] = s1[ch]; shv[r] = t1[ch];
    }
#pragma unroll
    for (int g = 0; g < 7; ++g) {
      const int pos = g * 16 + l15;
      if (pos < 100) {
        const int hr = pos / 10, hc = pos - hr * 10;
        const int r = tr0 + hr - 1, c = tc0 + hc - 1;
        uint2 pk = make_uint2(0u, 0u);
        if ((unsigned)r < 56u && (unsigned)c < 56u) {
          float v0 = fmaxf(fmaf(acc[g][0], scv[0], shv[0]), 0.f);
          float v1 = fmaxf(fmaf(acc[g][1], scv[1], shv[1]), 0.f);
          float v2 = fmaxf(fmaf(acc[g][2], scv[2], shv[2]), 0.f);
          float v3 = fmaxf(fmaf(acc[g][3], scv[3], shv[3]), 0.f);
          pk.x = (unsigned)f2b(v0) | ((unsigned)f2b(v1) << 16);
          pk.y = (unsigned)f2b(v2) | ((unsigned)f2b(v3) << 16);
        }
        *reinterpret_cast<uint2*>(&ot[pos * 76 + wm * 16 + lh * 4]) = pk;
      }
    }
    __syncthreads();   // ot + wsh ready

    // dw: thread handles 4 ch (q4) at 4 positions (pgrp*4+u)
    float wt[9][4];
#pragma unroll
    for (int tap = 0; tap < 9; ++tap) {
      const f32x4 wv = *reinterpret_cast<const f32x4*>(&wsh[tap * 64 + q4 * 4]);
      wt[tap][0] = wv[0]; wt[tap][1] = wv[1]; wt[tap][2] = wv[2]; wt[tap][3] = wv[3];
    }
    float psc[4] = {0.f, 0.f, 0.f, 0.f}, psq[4] = {0.f, 0.f, 0.f, 0.f};
#pragma unroll
    for (int u = 0; u < 4; ++u) {
      const int opos = pgrp * 4 + u;
      const int orr = opos >> 3, oc = opos & 7;
      float av[4] = {0.f, 0.f, 0.f, 0.f};
#pragma unroll
      for (int dy = 0; dy < 3; ++dy)
#pragma unroll
        for (int dx = 0; dx < 3; ++dx) {
          const int hpos = (orr + dy) * 10 + (oc + dx);
          const uint2 rv = *reinterpret_cast<const uint2*>(&ot[hpos * 76 + q4 * 4]);
          const int tap = dy * 3 + dx;
          av[0] = fmaf(wt[tap][0], b2f(rv.x), av[0]);
          av[1] = fmaf(wt[tap][1], b2f(rv.x >> 16), av[1]);
          av[2] = fmaf(wt[tap][2], b2f(rv.y), av[2]);
          av[3] = fmaf(wt[tap][3], b2f(rv.y >> 16), av[3]);
        }
      unsigned p0 = (unsigned)f2b(av[0]) | ((unsigned)f2b(av[1]) << 16);
      unsigned p1 = (unsigned)f2b(av[2]) | ((unsigned)f2b(av[3]) << 16);
      *reinterpret_cast<uint2*>(
          o2c + (size_t)(n * HW + (tr0 + orr) * 56 + tc0 + oc) * PL + kc * 64 + q4 * 4) =
          make_uint2(p0, p1);
#pragma unroll
      for (int j = 0; j < 4; ++j) { psc[j] += av[j]; psq[j] = fmaf(av[j], av[j], psq[j]); }
    }
    // BN2 partials: reduce 16 pos-groups -> wave, then cross-wave via LDS
#pragma unroll
    for (int j = 0; j < 4; ++j) {
      psc[j] += __shfl_xor(psc[j], 16); psc[j] += __shfl_xor(psc[j], 32);
      psq[j] += __shfl_xor(psq[j], 16); psq[j] += __shfl_xor(psq[j], 32);
    }
    if ((tid & 63) < 16) {
      const int wv_ = tid >> 6;
#pragma unroll
      for (int j = 0; j < 4; ++j) {
        red0[wv_ * 64 + q4 * 4 + j] = psc[j];
        red1[wv_ * 64 + q4 * 4 + j] = psq[j];
      }
    }
    __syncthreads();   // also protects ot for next kc
    if (tid < 64) {
      float a = red0[tid] + red0[64 + tid] + red0[128 + tid] + red0[192 + tid];
      float b = red1[tid] + red1[64 + tid] + red1[128 + tid] + red1[192 + tid];
      const int pi = (kc * 64 + tid) * 1568 + n * NT + tb;
      psum[pi] = a; psumsq[pi] = b;
    }
  }
}

// ---------------- conv3: 1x1 project 576->96, staged + XOR-swizzled LDS ---------
// grid (49, 32). block 256 = 4 waves in 2x2 (48 cout x 32 hw each).
__global__ __launch_bounds__(256) void conv3_mfma(
    const __hip_bfloat16* __restrict__ o2c, const __hip_bfloat16* __restrict__ tw3,
    const float* __restrict__ s2, const float* __restrict__ t2,
    __hip_bfloat16* __restrict__ out3,
    float* __restrict__ psum, float* __restrict__ psumsq) {
  __shared__ __hip_bfloat16 chunk[2][64 * 64];
  __shared__ float smem[96 * 65];
  __shared__ float s2s[PL], t2s[PL];
  const int hwt = blockIdx.x, n = blockIdx.y, tid = threadIdx.x;
  const int lane = tid & 63, w = tid >> 6;
  const int l15 = lane & 15, lh = lane >> 4;
  const int wm = w >> 1, wn = w & 1;
  const int t0 = hwt * 64;
  for (int i = tid; i < PL; i += 256) { s2s[i] = s2[i]; t2s[i] = t2[i]; }

  const int hwp = tid >> 2;
  const int cq = tid & 3;
  const __hip_bfloat16* src = o2c + ((size_t)n * HW + t0 + hwp) * PL + cq * 16;
  uint4 ra = *reinterpret_cast<const uint4*>(src);
  uint4 rb = *reinterpret_cast<const uint4*>(src + 8);

  f32x4 acc[3][2];
#pragma unroll
  for (int f = 0; f < 3; ++f)
#pragma unroll
    for (int g = 0; g < 2; ++g) acc[f][g] = (f32x4){0.f, 0.f, 0.f, 0.f};

  const unsigned key = (unsigned)((hwp & 7) << 4);
  __syncthreads();

  for (int kc = 0; kc < 9; ++kc) {
    const int cur = kc & 1;
    {
      const int cb16 = kc * 64 + cq * 16;
      unsigned uu[8] = {ra.x, ra.y, ra.z, ra.w, rb.x, rb.y, rb.z, rb.w};
      unsigned po[8];
#pragma unroll
      for (int j = 0; j < 8; ++j) {
        float lo = fmaxf(fmaf(b2f(uu[j]),       s2s[cb16 + 2 * j],     t2s[cb16 + 2 * j]), 0.f);
        float hi = fmaxf(fmaf(b2f(uu[j] >> 16), s2s[cb16 + 2 * j + 1], t2s[cb16 + 2 * j + 1]), 0.f);
        po[j] = (unsigned)f2b(lo) | ((unsigned)f2b(hi) << 16);
      }
      char* base = (char*)&chunk[cur][0] + hwp * 128;
      *reinterpret_cast<uint4*>(base + (((unsigned)(cq * 32)) ^ key)) =
          make_uint4(po[0], po[1], po[2], po[3]);
      *reinterpret_cast<uint4*>(base + (((unsigned)(cq * 32 + 16)) ^ key)) =
          make_uint4(po[4], po[5], po[6], po[7]);
    }
    __syncthreads();
    if (kc < 8) {
      ra = *reinterpret_cast<const uint4*>(src + (kc + 1) * 64);
      rb = *reinterpret_cast<const uint4*>(src + (kc + 1) * 64 + 8);
    }
#pragma unroll
    for (int kb = 0; kb < 2; ++kb) {
      s16x8 a[3];
#pragma unroll
      for (int f = 0; f < 3; ++f)
        a[f] = *reinterpret_cast<const s16x8*>(
            tw3 + (size_t)(wm * 48 + f * 16 + l15) * PL + kc * 64 + kb * 32 + lh * 8);
#pragma unroll
      for (int g = 0; g < 2; ++g) {
        const int row = wn * 32 + g * 16 + l15;
        const unsigned cbyte = (unsigned)(kb * 64 + lh * 16) ^ (unsigned)((row & 7) << 4);
        const s16x8 b = *reinterpret_cast<const s16x8*>(
            (const char*)&chunk[cur][0] + row * 128 + cbyte);
#pragma unroll
        for (int f = 0; f < 3; ++f)
          acc[f][g] = __builtin_amdgcn_mfma_f32_16x16x32_bf16(a[f], b, acc[f][g], 0, 0, 0);
      }
    }
  }
  __syncthreads();
#pragma unroll
  for (int f = 0; f < 3; ++f)
#pragma unroll
    for (int g = 0; g < 2; ++g)
#pragma unroll
      for (int r = 0; r < 4; ++r)
        smem[(wm * 48 + f * 16 + lh * 4 + r) * 65 + wn * 32 + g * 16 + l15] = acc[f][g][r];
  __syncthreads();
  const int slot = tid & 7, rgrp = tid >> 3;
#pragma unroll
  for (int s = 0; s < 3; ++s) {
    const int rl = s * 32 + rgrp;
    float v[8], sm = 0.f, sq = 0.f;
#pragma unroll
    for (int j = 0; j < 8; ++j) {
      float t = smem[rl * 65 + slot * 8 + j];
      v[j] = t; sm += t; sq = fmaf(t, t, sq);
    }
    unsigned pk[4];
#pragma unroll
    for (int j = 0; j < 4; ++j) pk[j] = (unsigned)f2b(v[2 * j]) | ((unsigned)f2b(v[2 * j + 1]) << 16);
    *reinterpret_cast<uint4*>(out3 + ((size_t)n * COUT + rl) * HW + t0 + slot * 8) =
        make_uint4(pk[0], pk[1], pk[2], pk[3]);
#pragma unroll
    for (int m = 1; m < 8; m <<= 1) { sm += __shfl_xor(sm, m, 8); sq += __shfl_xor(sq, m, 8); }
    if (slot == 0) { int pi = rl * 1568 + n * NT + hwt; psum[pi] = sm; psumsq[pi] = sq; }
  }
}

// ---------------- final: out = BN3(out3_bf16) + x -------------------------------
__global__ __launch_bounds__(256) void final_kernel(
    const __hip_bfloat16* __restrict__ out3, const float* __restrict__ x,
    const float* __restrict__ s3, const float* __restrict__ t3,
    float* __restrict__ out) {
  const int i = blockIdx.x * 256 + threadIdx.x;
  const int p = (i * 4) / HW;
  const int co = p - (p / COUT) * COUT;
  uint2 raw = reinterpret_cast<const uint2*>(out3)[i];
  float4 b = reinterpret_cast<const float4*>(x)[i];
  const float scv = s3[co], tv = t3[co];
  float4 r;
  r.x = fmaf(b2f(raw.x), scv, tv) + b.x;
  r.y = fmaf(b2f(raw.x >> 16), scv, tv) + b.y;
  r.z = fmaf(b2f(raw.y), scv, tv) + b.z;
  r.w = fmaf(b2f(raw.y >> 16), scv, tv) + b.w;
  reinterpret_cast<float4*>(out)[i] = r;
}

extern "C" void kernel_launch(void* const* d_in, const int* in_sizes, int n_in,
                              void* d_out, int out_size, void* d_ws, size_t ws_size,
                              hipStream_t stream) {
  const float* x  = (const float*)d_in[0];
  const float* w1 = (const float*)d_in[1];
  const float* g1 = (const float*)d_in[2];
  const float* b1 = (const float*)d_in[3];
  const float* w2 = (const float*)d_in[4];
  const float* g2 = (const float*)d_in[5];
  const float* b2 = (const float*)d_in[6];
  const float* w3 = (const float*)d_in[7];
  const float* g3 = (const float*)d_in[8];
  const float* b3 = (const float*)d_in[9];
  float* out = (float*)d_out;

  char* ws = (char*)d_ws;
  __hip_bfloat16* tw1b = (__hip_bfloat16*)(ws + 0);            // 110592 B
  __hip_bfloat16* tw3b = (__hip_bfloat16*)(ws + 110592);       // 110592 B
  float* tw2f = (float*)(ws + 221184);                          // 20736 B
  float* s1 = (float*)(ws + 241920);
  float* t1 = s1 + PL; float* s2 = t1 + PL; float* t2 = s2 + PL;
  float* s3 = (float*)(ws + 251136); float* t3 = s3 + COUT;
  float* ps1 = (float*)(ws + 251904);                           // 576*1568 f32
  float* pq1 = ps1 + PL * 1568;
  float* ps2 = pq1 + PL * 1568;                                 // 576*1568 f32
  float* pq2 = ps2 + PL * 1568;
  float* ps3 = pq2 + PL * 1568;                                 // 96*1568 f32
  float* pq3 = ps3 + COUT * 1568;
  float* part1 = pq3 + COUT * 1568;                              // 32 f32 each
  float* part2 = part1 + 32;
  float* part3 = part2 + 32;
  __hip_bfloat16* xb    = (__hip_bfloat16*)(ws + 16777216);              // 19.3 MB
  __hip_bfloat16* o2c   = (__hip_bfloat16*)(ws + 36175872);             // 115.6 MB
  __hip_bfloat16* out3b = (__hip_bfloat16*)(ws + 151781376);            // 19.3 MB

  // ternarize (parallel 2-stage, deterministic)
  absred_kernel<<<32, 256, 0, stream>>>(w1, part1, 13824);
  absred_kernel<<<32, 256, 0, stream>>>(w2, part2, 1296);
  absred_kernel<<<32, 256, 0, stream>>>(w3, part3, 13824);
  ternw_bf16_kernel<<<54, 256, 0, stream>>>(w1, part1, 1.0f / 55296.0f, tw1b, 13824);
  ternw_f32_kernel <<<6, 256, 0, stream>>>(w2, part2, 1.0f / 5184.0f, tw2f, 1296);
  ternw_bf16_kernel<<<54, 256, 0, stream>>>(w3, part3, 1.0f / 55296.0f, tw3b, 13824);

  xcast_kernel<<<dim3(NT, BATCH), 256, 0, stream>>>(x, xb);
  conv1_stats<<<dim3(NT, BATCH, 3), 256, 0, stream>>>(x, tw1b, ps1, pq1);
  bnp_kernel<<<PL, 256, 0, stream>>>(ps1, pq1, g1, b1, s1, t1, 1568);

  fused_kernel<<<dim3(NT, BATCH), 256, 0, stream>>>(xb, tw1b, tw2f, s1, t1, o2c, ps2, pq2);
  bnp_kernel<<<PL, 256, 0, stream>>>(ps2, pq2, g2, b2, s2, t2, 1568);

  conv3_mfma<<<dim3(NT, BATCH), 256, 0, stream>>>(o2c, tw3b, s2, t2, out3b, ps3, pq3);
  bnp_kernel<<<COUT, 256, 0, stream>>>(ps3, pq3, g3, b3, s3, t3, 1568);

  final_kernel<<<out_size / 1024, 256, 0, stream>>>(out3b, x, s3, t3, out);
}

// Round 11
// 236.928 us; speedup vs baseline: 1.2308x; 1.2308x over previous
//
#include <hip/hip_runtime.h>
#include <hip/hip_bf16.h>

// B=32, Cin=96, HW=3136 (56x56), planes=576, Cout=96. hw tiles: 49 x 64 (exact).
#define BATCH 32
#define CIN 96
#define HW 3136
#define PL 576
#define COUT 96
#define NT 49
#define NHW 100352.0

typedef __attribute__((ext_vector_type(4))) float f32x4;
typedef __attribute__((ext_vector_type(8))) short s16x8;

__device__ __forceinline__ unsigned short f2b(float v) {
  __hip_bfloat16 h = __float2bfloat16(v);
  return *reinterpret_cast<unsigned short*>(&h);
}
__device__ __forceinline__ float b2f(unsigned int u) {
  return __uint_as_float((u & 0xffffu) << 16);
}

// ---------------- ternarize, parallel: stage 1 = partial |w| sums ---------------
__global__ __launch_bounds__(256) void absred_kernel(const float* __restrict__ w,
                                                     float* __restrict__ part, int n4) {
  __shared__ float ra[256];
  const int tid = threadIdx.x;
  float s = 0.f;
  for (int i = blockIdx.x * 256 + tid; i < n4; i += 32 * 256) {
    float4 v = reinterpret_cast<const float4*>(w)[i];
    s += fabsf(v.x) + fabsf(v.y) + fabsf(v.z) + fabsf(v.w);
  }
  ra[tid] = s; __syncthreads();
  for (int off = 128; off; off >>= 1) { if (tid < off) ra[tid] += ra[tid + off]; __syncthreads(); }
  if (tid == 0) part[blockIdx.x] = ra[0];
}

__device__ __forceinline__ float delta_from_parts(const float* __restrict__ part, float invn) {
  float s = 0.f;
#pragma unroll
  for (int i = 0; i < 32; ++i) s += part[i];
  return 0.7f * s * invn;
}

__global__ __launch_bounds__(256) void ternw_bf16_kernel(
    const float* __restrict__ w, const float* __restrict__ part, float invn,
    __hip_bfloat16* __restrict__ tw, int n4) {
  const float delta = delta_from_parts(part, invn);
  const int i = blockIdx.x * 256 + threadIdx.x;
  if (i >= n4) return;
  float4 v = reinterpret_cast<const float4*>(w)[i];
  float vv[4] = {v.x, v.y, v.z, v.w};
  unsigned short b[4];
#pragma unroll
  for (int j = 0; j < 4; ++j)
    b[j] = (fabsf(vv[j]) > delta)
               ? (unsigned short)(0x3F80u | ((__float_as_uint(vv[j]) >> 16) & 0x8000u))
               : (unsigned short)0;
  unsigned lo = (unsigned)b[0] | ((unsigned)b[1] << 16);
  unsigned hi = (unsigned)b[2] | ((unsigned)b[3] << 16);
  reinterpret_cast<uint2*>(tw)[i] = make_uint2(lo, hi);
}

__global__ __launch_bounds__(256) void ternw_f32_kernel(
    const float* __restrict__ w, const float* __restrict__ part, float invn,
    float* __restrict__ tw, int n4) {
  const float delta = delta_from_parts(part, invn);
  const int i = blockIdx.x * 256 + threadIdx.x;
  if (i >= n4) return;
  float4 v = reinterpret_cast<const float4*>(w)[i];
  float4 o;
  o.x = (fabsf(v.x) > delta) ? (v.x > 0.f ? 1.f : -1.f) : 0.f;
  o.y = (fabsf(v.y) > delta) ? (v.y > 0.f ? 1.f : -1.f) : 0.f;
  o.z = (fabsf(v.z) > delta) ? (v.z > 0.f ? 1.f : -1.f) : 0.f;
  o.w = (fabsf(v.w) > delta) ? (v.w > 0.f ? 1.f : -1.f) : 0.f;
  reinterpret_cast<float4*>(tw)[i] = o;
}

// ---------------- BN param: sc = g*inv, sh = b - mean*g*inv ---------------------
__global__ __launch_bounds__(256) void bnp_kernel(
    const float* __restrict__ psum, const float* __restrict__ psumsq,
    const float* __restrict__ gamma, const float* __restrict__ beta,
    float* __restrict__ sc, float* __restrict__ sh, int nparts) {
  const int ch = blockIdx.x, tid = threadIdx.x;
  double s = 0.0, q = 0.0;
  for (int i = tid; i < nparts; i += 256) {
    s += (double)psum[(size_t)ch * nparts + i];
    q += (double)psumsq[(size_t)ch * nparts + i];
  }
  __shared__ double rs[256], rq[256];
  rs[tid] = s; rq[tid] = q; __syncthreads();
  for (int off = 128; off; off >>= 1) {
    if (tid < off) { rs[tid] += rs[tid + off]; rq[tid] += rq[tid + off]; }
    __syncthreads();
  }
  if (tid == 0) {
    double mean = rs[0] / NHW;
    double var = rq[0] / NHW - mean * mean;
    float inv = (float)(1.0 / sqrt(var + 1e-5));
    float g = gamma[ch];
    sc[ch] = inv * g;
    sh[ch] = beta[ch] - (float)mean * inv * g;
  }
}

// ---------------- conv1: 1x1 expand 96->576 via bf16 MFMA -----------------------
// grid (49, 32, 3): hw-tile 64, batch, M-tile 192. block 256 (4 waves x 48 rows).
// Epilogue: LDS-assembled channel-last stores (full 64B sectors, no write-amp).
__global__ __launch_bounds__(256) void conv1_mfma(
    const float* __restrict__ x, const __hip_bfloat16* __restrict__ tw1,
    __hip_bfloat16* __restrict__ o1c,
    float* __restrict__ psum, float* __restrict__ psumsq) {
  __shared__ __hip_bfloat16 Bt[64 * 104];   // 13.3 KB B-tile [hw][c]
  __shared__ __hip_bfloat16 ot[64 * 200];   // 25.6 KB out-tile [hw][ch], pad->2-way max
  const int hwt = blockIdx.x, n = blockIdx.y, mt = blockIdx.z;
  const int t0 = hwt * 64;
  const int tid = threadIdx.x;
  const int lane = tid & 63, w = tid >> 6;

  // stage B: x[c][t0+lane] -> Bt[lane][c] (bf16, row stride 104)
  {
    const float* xp = x + (size_t)n * CIN * HW + t0 + lane;
    const int cb = w * 24;
#pragma unroll
    for (int i6 = 0; i6 < 6; ++i6) {
      const int c0 = cb + i6 * 4;
      float v0 = xp[(size_t)(c0 + 0) * HW];
      float v1 = xp[(size_t)(c0 + 1) * HW];
      float v2 = xp[(size_t)(c0 + 2) * HW];
      float v3 = xp[(size_t)(c0 + 3) * HW];
      unsigned lo = (unsigned)f2b(v0) | ((unsigned)f2b(v1) << 16);
      unsigned hi = (unsigned)f2b(v2) | ((unsigned)f2b(v3) << 16);
      *reinterpret_cast<uint2*>(&Bt[lane * 104 + c0]) = make_uint2(lo, hi);
    }
  }
  __syncthreads();

  const int l15 = lane & 15, lh = lane >> 4;
  f32x4 acc[3][4];
#pragma unroll
  for (int f = 0; f < 3; ++f)
#pragma unroll
    for (int g = 0; g < 4; ++g) acc[f][g] = (f32x4){0.f, 0.f, 0.f, 0.f};
  const int rowb = mt * 192 + w * 48;
#pragma unroll
  for (int k0 = 0; k0 < 3; ++k0) {
    s16x8 a[3], b[4];
#pragma unroll
    for (int f = 0; f < 3; ++f)
      a[f] = *reinterpret_cast<const s16x8*>(tw1 + (size_t)(rowb + f * 16 + l15) * CIN + k0 * 32 + lh * 8);
#pragma unroll
    for (int g = 0; g < 4; ++g)
      b[g] = *reinterpret_cast<const s16x8*>(&Bt[(g * 16 + l15) * 104 + k0 * 32 + lh * 8]);
#pragma unroll
    for (int f = 0; f < 3; ++f)
#pragma unroll
      for (int g = 0; g < 4; ++g)
        acc[f][g] = __builtin_amdgcn_mfma_f32_16x16x32_bf16(a[f], b[g], acc[f][g], 0, 0, 0);
  }

  // BN partials from acc (register-side, width-16 shuffles)
#pragma unroll
  for (int f = 0; f < 3; ++f) {
    float sred[4] = {0.f, 0.f, 0.f, 0.f};
    float qred[4] = {0.f, 0.f, 0.f, 0.f};
    const int ch0 = rowb + f * 16 + lh * 4;
#pragma unroll
    for (int g = 0; g < 4; ++g)
#pragma unroll
      for (int r = 0; r < 4; ++r) {
        float v = acc[f][g][r];
        sred[r] += v; qred[r] = fmaf(v, v, qred[r]);
      }
#pragma unroll
    for (int r = 0; r < 4; ++r) {
      float s = sred[r], q = qred[r];
#pragma unroll
      for (int m = 1; m < 16; m <<= 1) { s += __shfl_xor(s, m); q += __shfl_xor(q, m); }
      if (l15 == 0) {
        const int pi = (ch0 + r) * 1568 + n * NT + hwt;
        psum[pi] = s; psumsq[pi] = q;
      }
    }
  }

  // pass 1: acc -> ot[hw][ch] (uint2 per lane; <=2-way bank aliasing = free)
#pragma unroll
  for (int f = 0; f < 3; ++f) {
    const int chL = w * 48 + f * 16 + lh * 4;
#pragma unroll
    for (int g = 0; g < 4; ++g) {
      unsigned p0 = (unsigned)f2b(acc[f][g][0]) | ((unsigned)f2b(acc[f][g][1]) << 16);
      unsigned p1 = (unsigned)f2b(acc[f][g][2]) | ((unsigned)f2b(acc[f][g][3]) << 16);
      *reinterpret_cast<uint2*>(&ot[(g * 16 + l15) * 200 + chL]) = make_uint2(p0, p1);
    }
  }
  __syncthreads();

  // pass 2: full-sector stores: 4 consecutive lanes cover 64B contiguous channels
  {
    const int hwp = tid >> 2, q = tid & 3;
    const __hip_bfloat16* src = &ot[hwp * 200];
    __hip_bfloat16* dst = o1c + ((size_t)n * HW + t0 + hwp) * PL + mt * 192;
#pragma unroll
    for (int s = 0; s < 6; ++s) {
      const int c8 = q + s * 4;   // 16B chunk index, 24 chunks = 192 ch
      *reinterpret_cast<uint4*>(dst + c8 * 8) =
          *reinterpret_cast<const uint4*>(src + c8 * 8);
    }
  }
}

// ---------------- depthwise 3x3: register rolling window, deep pipeline ---------
// grid (14 col-strips of 4, 9 ch-chunks of 64, 32 batch). block 64 (1 wave).
// lane = col(0..3)*16 + chs(0..15); each lane owns 4 channels of one column.
// 16 consecutive lanes = 64 ch * 2B = one FULL 128B line per column per load.
// 8-slot raw queue (prefetch distance 7 rows) + 4-slot converted window ring.
__global__ __launch_bounds__(64) void dw_kernel(
    const __hip_bfloat16* __restrict__ o1c, const float* __restrict__ tw2,
    const float* __restrict__ s1, const float* __restrict__ t1,
    __hip_bfloat16* __restrict__ o2c,
    float* __restrict__ psum, float* __restrict__ psumsq) {
  const int strip = blockIdx.x, kh = blockIdx.y, n = blockIdx.z;
  const int lane = threadIdx.x;
  const int col = lane >> 4, chs = lane & 15;
  const int c = strip * 4 + col;
  const int chb = kh * 64 + chs * 4;
  const int ec = (col == 0) ? (c - 1) : (c + 1);   // halo column this lane may load
  const bool eok = (col == 0) ? (c > 0) : ((col == 3) ? (c < 55) : false);

  float sc[4], sh[4], wt[9][4];
#pragma unroll
  for (int j = 0; j < 4; ++j) {
    sc[j] = s1[chb + j]; sh[j] = t1[chb + j];
#pragma unroll
    for (int t = 0; t < 9; ++t) wt[t][j] = tw2[(chb + j) * 9 + t];
  }

  const size_t nb = (size_t)n * HW;
  const __hip_bfloat16* pc = o1c + (nb + c) * PL + chb;
  const __hip_bfloat16* pe = o1c + (nb + ((eok ? ec : c))) * PL + chb;
  __hip_bfloat16* po = o2c + (nb + c) * PL + chb;

  uint2 rc[8], re[8];
  float Wl[4][4], Wc[4][4], Wr[4][4];
  float psc[4] = {0.f, 0.f, 0.f, 0.f}, psq[4] = {0.f, 0.f, 0.f, 0.f};

#define LOADRAW(s, q_) do {                                                    \
    rc[s] = make_uint2(0u, 0u); re[s] = make_uint2(0u, 0u);                    \
    if ((q_) < 56) {                                                           \
      rc[s] = *reinterpret_cast<const uint2*>(pc + (size_t)(q_) * 56 * PL);    \
      if (eok) re[s] = *reinterpret_cast<const uint2*>(pe + (size_t)(q_) * 56 * PL); \
    } } while (0)

#define BN4(dst, raw) do {                                                     \
    dst[0] = fmaxf(fmaf(b2f((raw).x), sc[0], sh[0]), 0.f);                     \
    dst[1] = fmaxf(fmaf(b2f((raw).x >> 16), sc[1], sh[1]), 0.f);               \
    dst[2] = fmaxf(fmaf(b2f((raw).y), sc[2], sh[2]), 0.f);                     \
    dst[3] = fmaxf(fmaf(b2f((raw).y >> 16), sc[3], sh[3]), 0.f);               \
  } while (0)

#define CONVW(wi, s, q_) do {                                                  \
    if ((q_) < 56) {                                                           \
      float cen_[4], ee_[4];                                                   \
      BN4(cen_, rc[s]); BN4(ee_, re[s]);                                       \
      _Pragma("unroll")                                                        \
      for (int j = 0; j < 4; ++j) {                                            \
        float lv = __shfl(cen_[j], lane - 16);                                 \
        float rv = __shfl(cen_[j], lane + 16);                                 \
        float ev = eok ? ee_[j] : 0.f;                                         \
        Wc[wi][j] = cen_[j];                                                   \
        Wl[wi][j] = (col == 0) ? ev : lv;                                      \
        Wr[wi][j] = (col == 3) ? ev : rv;                                      \
      }                                                                        \
    } else {                                                                   \
      _Pragma("unroll")                                                        \
      for (int j = 0; j < 4; ++j) { Wl[wi][j] = 0.f; Wc[wi][j] = 0.f; Wr[wi][j] = 0.f; } \
    } } while (0)

#define COMPW(qm, q0, qp, q_) do {                                             \
    float o_[4];                                                               \
    _Pragma("unroll")                                                          \
    for (int j = 0; j < 4; ++j) {                                              \
      float a_ = wt[0][j] * Wl[qm][j];                                         \
      a_ = fmaf(wt[1][j], Wc[qm][j], a_);                                      \
      a_ = fmaf(wt[2][j], Wr[qm][j], a_);                                      \
      a_ = fmaf(wt[3][j], Wl[q0][j], a_);                                      \
      a_ = fmaf(wt[4][j], Wc[q0][j], a_);                                      \
      a_ = fmaf(wt[5][j], Wr[q0][j], a_);                                      \
      a_ = fmaf(wt[6][j], Wl[qp][j], a_);                                      \
      a_ = fmaf(wt[7][j], Wc[qp][j], a_);                                      \
      a_ = fmaf(wt[8][j], Wr[qp][j], a_);                                      \
      o_[j] = a_;                                                              \
      psc[j] += a_; psq[j] = fmaf(a_, a_, psq[j]);                             \
    }                                                                          \
    unsigned pk0 = (unsigned)f2b(o_[0]) | ((unsigned)f2b(o_[1]) << 16);        \
    unsigned pk1 = (unsigned)f2b(o_[2]) | ((unsigned)f2b(o_[3]) << 16);        \
    *reinterpret_cast<uint2*>(po + (size_t)(q_) * 56 * PL) = make_uint2(pk0, pk1); \
  } while (0)

  // prologue: rows 0..7 in flight (16 independent loads); convert row 0;
  // window slot 3 = row -1 = zeros.
  LOADRAW(0, 0); LOADRAW(1, 1); LOADRAW(2, 2); LOADRAW(3, 3);
  LOADRAW(4, 4); LOADRAW(5, 5); LOADRAW(6, 6); LOADRAW(7, 7);
  CONVW(0, 0, 0);
#pragma unroll
  for (int j = 0; j < 4; ++j) { Wl[3][j] = 0.f; Wc[3][j] = 0.f; Wr[3][j] = 0.f; }

  for (int t = 0; t < 7; ++t) {
    const int q = 8 * t;
    LOADRAW(0, q + 8);  CONVW(1, 1, q + 1);  COMPW(3, 0, 1, q);
    LOADRAW(1, q + 9);  CONVW(2, 2, q + 2);  COMPW(0, 1, 2, q + 1);
    LOADRAW(2, q + 10); CONVW(3, 3, q + 3);  COMPW(1, 2, 3, q + 2);
    LOADRAW(3, q + 11); CONVW(0, 4, q + 4);  COMPW(2, 3, 0, q + 3);
    LOADRAW(4, q + 12); CONVW(1, 5, q + 5);  COMPW(3, 0, 1, q + 4);
    LOADRAW(5, q + 13); CONVW(2, 6, q + 6);  COMPW(0, 1, 2, q + 5);
    LOADRAW(6, q + 14); CONVW(3, 7, q + 7);  COMPW(1, 2, 3, q + 6);
    LOADRAW(7, q + 15); CONVW(0, 0, q + 8);  COMPW(2, 3, 0, q + 7);
  }
#undef COMPW
#undef CONVW
#undef BN4
#undef LOADRAW

  // BN2 partials: reduce over the wave's 4 columns (lanes differing in bits 4-5)
#pragma unroll
  for (int j = 0; j < 4; ++j) {
    psc[j] += __shfl_xor(psc[j], 16); psc[j] += __shfl_xor(psc[j], 32);
    psq[j] += __shfl_xor(psq[j], 16); psq[j] += __shfl_xor(psq[j], 32);
  }
  if (col == 0) {
#pragma unroll
    for (int j = 0; j < 4; ++j) {
      const int pi = (chb + j) * 448 + n * 14 + strip;
      psum[pi] = psc[j]; psumsq[pi] = psq[j];
    }
  }
}

// ---------------- conv3: 1x1 project 576->96, staged + XOR-swizzled LDS ---------
// grid (49, 32). block 256 = 4 waves in 2x2 (48 cout x 32 hw each).
__global__ __launch_bounds__(256) void conv3_mfma(
    const __hip_bfloat16* __restrict__ o2c, const __hip_bfloat16* __restrict__ tw3,
    const float* __restrict__ s2, const float* __restrict__ t2,
    __hip_bfloat16* __restrict__ out3,
    float* __restrict__ psum, float* __restrict__ psumsq) {
  __shared__ __hip_bfloat16 chunk[2][64 * 64];   // 16 KB dbuf: [hw][ch], XOR-swizzled
  __shared__ float smem[96 * 65];                // 24.96 KB epilogue bounce
  __shared__ float s2s[PL], t2s[PL];
  const int hwt = blockIdx.x, n = blockIdx.y, tid = threadIdx.x;
  const int lane = tid & 63, w = tid >> 6;
  const int l15 = lane & 15, lh = lane >> 4;
  const int wm = w >> 1, wn = w & 1;
  const int t0 = hwt * 64;
  for (int i = tid; i < PL; i += 256) { s2s[i] = s2[i]; t2s[i] = t2[i]; }

  const int hwp = tid >> 2;          // 0..63
  const int cq = tid & 3;            // 16-ch group
  const __hip_bfloat16* src = o2c + ((size_t)n * HW + t0 + hwp) * PL + cq * 16;
  uint4 ra = *reinterpret_cast<const uint4*>(src);
  uint4 rb = *reinterpret_cast<const uint4*>(src + 8);

  f32x4 acc[3][2];
#pragma unroll
  for (int f = 0; f < 3; ++f)
#pragma unroll
    for (int g = 0; g < 2; ++g) acc[f][g] = (f32x4){0.f, 0.f, 0.f, 0.f};

  const unsigned key = (unsigned)((hwp & 7) << 4);
  __syncthreads();   // s2s ready

  for (int kc = 0; kc < 9; ++kc) {
    const int cur = kc & 1;
    {
      const int cb16 = kc * 64 + cq * 16;
      unsigned uu[8] = {ra.x, ra.y, ra.z, ra.w, rb.x, rb.y, rb.z, rb.w};
      unsigned po[8];
#pragma unroll
      for (int j = 0; j < 8; ++j) {
        float lo = fmaxf(fmaf(b2f(uu[j]),       s2s[cb16 + 2 * j],     t2s[cb16 + 2 * j]), 0.f);
        float hi = fmaxf(fmaf(b2f(uu[j] >> 16), s2s[cb16 + 2 * j + 1], t2s[cb16 + 2 * j + 1]), 0.f);
        po[j] = (unsigned)f2b(lo) | ((unsigned)f2b(hi) << 16);
      }
      char* base = (char*)&chunk[cur][0] + hwp * 128;
      *reinterpret_cast<uint4*>(base + (((unsigned)(cq * 32)) ^ key)) =
          make_uint4(po[0], po[1], po[2], po[3]);
      *reinterpret_cast<uint4*>(base + (((unsigned)(cq * 32 + 16)) ^ key)) =
          make_uint4(po[4], po[5], po[6], po[7]);
    }
    __syncthreads();
    if (kc < 8) {
      ra = *reinterpret_cast<const uint4*>(src + (kc + 1) * 64);
      rb = *reinterpret_cast<const uint4*>(src + (kc + 1) * 64 + 8);
    }
#pragma unroll
    for (int kb = 0; kb < 2; ++kb) {
      s16x8 a[3];
#pragma unroll
      for (int f = 0; f < 3; ++f)
        a[f] = *reinterpret_cast<const s16x8*>(
            tw3 + (size_t)(wm * 48 + f * 16 + l15) * PL + kc * 64 + kb * 32 + lh * 8);
#pragma unroll
      for (int g = 0; g < 2; ++g) {
        const int row = wn * 32 + g * 16 + l15;
        const unsigned cbyte = (unsigned)(kb * 64 + lh * 16) ^ (unsigned)((row & 7) << 4);
        const s16x8 b = *reinterpret_cast<const s16x8*>(
            (const char*)&chunk[cur][0] + row * 128 + cbyte);
#pragma unroll
        for (int f = 0; f < 3; ++f)
          acc[f][g] = __builtin_amdgcn_mfma_f32_16x16x32_bf16(a[f], b, acc[f][g], 0, 0, 0);
      }
    }
  }
  __syncthreads();
#pragma unroll
  for (int f = 0; f < 3; ++f)
#pragma unroll
    for (int g = 0; g < 2; ++g)
#pragma unroll
      for (int r = 0; r < 4; ++r)
        smem[(wm * 48 + f * 16 + lh * 4 + r) * 65 + wn * 32 + g * 16 + l15] = acc[f][g][r];
  __syncthreads();
  const int slot = tid & 7, rgrp = tid >> 3;
#pragma unroll
  for (int s = 0; s < 3; ++s) {
    const int rl = s * 32 + rgrp;
    float v[8], sm = 0.f, sq = 0.f;
#pragma unroll
    for (int j = 0; j < 8; ++j) {
      float t = smem[rl * 65 + slot * 8 + j];
      v[j] = t; sm += t; sq = fmaf(t, t, sq);
    }
    unsigned pk[4];
#pragma unroll
    for (int j = 0; j < 4; ++j) pk[j] = (unsigned)f2b(v[2 * j]) | ((unsigned)f2b(v[2 * j + 1]) << 16);
    *reinterpret_cast<uint4*>(out3 + ((size_t)n * COUT + rl) * HW + t0 + slot * 8) =
        make_uint4(pk[0], pk[1], pk[2], pk[3]);
#pragma unroll
    for (int m = 1; m < 8; m <<= 1) { sm += __shfl_xor(sm, m, 8); sq += __shfl_xor(sq, m, 8); }
    if (slot == 0) { int pi = rl * 1568 + n * NT + hwt; psum[pi] = sm; psumsq[pi] = sq; }
  }
}

// ---------------- final: out = BN3(out3_bf16) + x -------------------------------
__global__ __launch_bounds__(256) void final_kernel(
    const __hip_bfloat16* __restrict__ out3, const float* __restrict__ x,
    const float* __restrict__ s3, const float* __restrict__ t3,
    float* __restrict__ out) {
  const int i = blockIdx.x * 256 + threadIdx.x;   // float4 index, grid exact
  const int p = (i * 4) / HW;
  const int co = p - (p / COUT) * COUT;
  uint2 raw = reinterpret_cast<const uint2*>(out3)[i];
  float4 b = reinterpret_cast<const float4*>(x)[i];
  const float scv = s3[co], tv = t3[co];
  float4 r;
  r.x = fmaf(b2f(raw.x), scv, tv) + b.x;
  r.y = fmaf(b2f(raw.x >> 16), scv, tv) + b.y;
  r.z = fmaf(b2f(raw.y), scv, tv) + b.z;
  r.w = fmaf(b2f(raw.y >> 16), scv, tv) + b.w;
  reinterpret_cast<float4*>(out)[i] = r;
}

extern "C" void kernel_launch(void* const* d_in, const int* in_sizes, int n_in,
                              void* d_out, int out_size, void* d_ws, size_t ws_size,
                              hipStream_t stream) {
  const float* x  = (const float*)d_in[0];
  const float* w1 = (const float*)d_in[1];
  const float* g1 = (const float*)d_in[2];
  const float* b1 = (const float*)d_in[3];
  const float* w2 = (const float*)d_in[4];
  const float* g2 = (const float*)d_in[5];
  const float* b2 = (const float*)d_in[6];
  const float* w3 = (const float*)d_in[7];
  const float* g3 = (const float*)d_in[8];
  const float* b3 = (const float*)d_in[9];
  float* out = (float*)d_out;

  char* ws = (char*)d_ws;
  __hip_bfloat16* tw1b = (__hip_bfloat16*)(ws + 0);            // 110592 B
  __hip_bfloat16* tw3b = (__hip_bfloat16*)(ws + 110592);       // 110592 B
  float* tw2f = (float*)(ws + 221184);                          // 20736 B
  float* s1 = (float*)(ws + 241920);
  float* t1 = s1 + PL; float* s2 = t1 + PL; float* t2 = s2 + PL;
  float* s3 = (float*)(ws + 251136); float* t3 = s3 + COUT;
  float* ps1 = (float*)(ws + 251904);                           // 576*1568 f32
  float* pq1 = ps1 + PL * 1568;
  float* ps2 = pq1 + PL * 1568;                                 // 576*448 used
  float* pq2 = ps2 + PL * 1568;
  float* ps3 = pq2 + PL * 1568;                                 // 96*1568 f32
  float* pq3 = ps3 + COUT * 1568;
  float* part1 = pq3 + COUT * 1568;                              // 32 f32 each
  float* part2 = part1 + 32;
  float* part3 = part2 + 32;
  // o1c at 16 MB; o2c after. out3b ALIASES o1c (o1c dead once dw completes).
  __hip_bfloat16* o1c = (__hip_bfloat16*)(ws + 16777216);                 // 115.6 MB
  __hip_bfloat16* o2c = o1c + (size_t)BATCH * HW * PL;                    // 115.6 MB
  __hip_bfloat16* out3b = o1c;                                            // alias

  // ternarize (parallel 2-stage, deterministic)
  absred_kernel<<<32, 256, 0, stream>>>(w1, part1, 13824);
  absred_kernel<<<32, 256, 0, stream>>>(w2, part2, 1296);
  absred_kernel<<<32, 256, 0, stream>>>(w3, part3, 13824);
  ternw_bf16_kernel<<<54, 256, 0, stream>>>(w1, part1, 1.0f / 55296.0f, tw1b, 13824);
  ternw_f32_kernel <<<6, 256, 0, stream>>>(w2, part2, 1.0f / 5184.0f, tw2f, 1296);
  ternw_bf16_kernel<<<54, 256, 0, stream>>>(w3, part3, 1.0f / 55296.0f, tw3b, 13824);

  conv1_mfma<<<dim3(NT, BATCH, 3), 256, 0, stream>>>(x, tw1b, o1c, ps1, pq1);
  bnp_kernel<<<PL, 256, 0, stream>>>(ps1, pq1, g1, b1, s1, t1, 1568);

  dw_kernel<<<dim3(14, 9, BATCH), 64, 0, stream>>>(o1c, tw2f, s1, t1, o2c, ps2, pq2);
  bnp_kernel<<<PL, 256, 0, stream>>>(ps2, pq2, g2, b2, s2, t2, 448);

  conv3_mfma<<<dim3(NT, BATCH), 256, 0, stream>>>(o2c, tw3b, s2, t2, out3b, ps3, pq3);
  bnp_kernel<<<COUT, 256, 0, stream>>>(ps3, pq3, g3, b3, s3, t3, 1568);

  final_kernel<<<out_size / 1024, 256, 0, stream>>>(out3b, x, s3, t3, out);
}

// Round 12
// 225.557 us; speedup vs baseline: 1.2928x; 1.0504x over previous
//
#include <hip/hip_runtime.h>
#include <hip/hip_bf16.h>

// B=32, Cin=96, HW=3136 (56x56), planes=576, Cout=96. hw tiles: 49 x 64 (exact).
#define BATCH 32
#define CIN 96
#define HW 3136
#define PL 576
#define COUT 96
#define NT 49
#define NHW 100352.0

typedef __attribute__((ext_vector_type(4))) float f32x4;
typedef __attribute__((ext_vector_type(8))) short s16x8;

__device__ __forceinline__ unsigned short f2b(float v) {
  __hip_bfloat16 h = __float2bfloat16(v);
  return *reinterpret_cast<unsigned short*>(&h);
}
__device__ __forceinline__ float b2f(unsigned int u) {
  return __uint_as_float((u & 0xffffu) << 16);
}

// ---------------- ternarize, parallel: stage 1 = partial |w| sums ---------------
__global__ __launch_bounds__(256) void absred_kernel(const float* __restrict__ w,
                                                     float* __restrict__ part, int n4) {
  __shared__ float ra[256];
  const int tid = threadIdx.x;
  float s = 0.f;
  for (int i = blockIdx.x * 256 + tid; i < n4; i += 32 * 256) {
    float4 v = reinterpret_cast<const float4*>(w)[i];
    s += fabsf(v.x) + fabsf(v.y) + fabsf(v.z) + fabsf(v.w);
  }
  ra[tid] = s; __syncthreads();
  for (int off = 128; off; off >>= 1) { if (tid < off) ra[tid] += ra[tid + off]; __syncthreads(); }
  if (tid == 0) part[blockIdx.x] = ra[0];
}

__device__ __forceinline__ float delta_from_parts(const float* __restrict__ part, float invn) {
  float s = 0.f;
#pragma unroll
  for (int i = 0; i < 32; ++i) s += part[i];
  return 0.7f * s * invn;
}

__global__ __launch_bounds__(256) void ternw_bf16_kernel(
    const float* __restrict__ w, const float* __restrict__ part, float invn,
    __hip_bfloat16* __restrict__ tw, int n4) {
  const float delta = delta_from_parts(part, invn);
  const int i = blockIdx.x * 256 + threadIdx.x;
  if (i >= n4) return;
  float4 v = reinterpret_cast<const float4*>(w)[i];
  float vv[4] = {v.x, v.y, v.z, v.w};
  unsigned short b[4];
#pragma unroll
  for (int j = 0; j < 4; ++j)
    b[j] = (fabsf(vv[j]) > delta)
               ? (unsigned short)(0x3F80u | ((__float_as_uint(vv[j]) >> 16) & 0x8000u))
               : (unsigned short)0;
  unsigned lo = (unsigned)b[0] | ((unsigned)b[1] << 16);
  unsigned hi = (unsigned)b[2] | ((unsigned)b[3] << 16);
  reinterpret_cast<uint2*>(tw)[i] = make_uint2(lo, hi);
}

__global__ __launch_bounds__(256) void ternw_f32_kernel(
    const float* __restrict__ w, const float* __restrict__ part, float invn,
    float* __restrict__ tw, int n4) {
  const float delta = delta_from_parts(part, invn);
  const int i = blockIdx.x * 256 + threadIdx.x;
  if (i >= n4) return;
  float4 v = reinterpret_cast<const float4*>(w)[i];
  float4 o;
  o.x = (fabsf(v.x) > delta) ? (v.x > 0.f ? 1.f : -1.f) : 0.f;
  o.y = (fabsf(v.y) > delta) ? (v.y > 0.f ? 1.f : -1.f) : 0.f;
  o.z = (fabsf(v.z) > delta) ? (v.z > 0.f ? 1.f : -1.f) : 0.f;
  o.w = (fabsf(v.w) > delta) ? (v.w > 0.f ? 1.f : -1.f) : 0.f;
  reinterpret_cast<float4*>(tw)[i] = o;
}

// ---------------- BN param: sc = g*inv, sh = b - mean*g*inv ---------------------
__global__ __launch_bounds__(256) void bnp_kernel(
    const float* __restrict__ psum, const float* __restrict__ psumsq,
    const float* __restrict__ gamma, const float* __restrict__ beta,
    float* __restrict__ sc, float* __restrict__ sh, int nparts) {
  const int ch = blockIdx.x, tid = threadIdx.x;
  double s = 0.0, q = 0.0;
  for (int i = tid; i < nparts; i += 256) {
    s += (double)psum[(size_t)ch * nparts + i];
    q += (double)psumsq[(size_t)ch * nparts + i];
  }
  __shared__ double rs[256], rq[256];
  rs[tid] = s; rq[tid] = q; __syncthreads();
  for (int off = 128; off; off >>= 1) {
    if (tid < off) { rs[tid] += rs[tid + off]; rq[tid] += rq[tid + off]; }
    __syncthreads();
  }
  if (tid == 0) {
    double mean = rs[0] / NHW;
    double var = rq[0] / NHW - mean * mean;
    float inv = (float)(1.0 / sqrt(var + 1e-5));
    float g = gamma[ch];
    sc[ch] = inv * g;
    sh[ch] = beta[ch] - (float)mean * inv * g;
  }
}

// ---------------- conv1: 1x1 expand 96->576 via bf16 MFMA -----------------------
// grid (49, 32, 3): hw-tile 64, batch, M-tile 192. block 256 (4 waves x 48 rows).
// Epilogue: LDS-assembled channel-last stores (full 64B sectors, no write-amp).
__global__ __launch_bounds__(256) void conv1_mfma(
    const float* __restrict__ x, const __hip_bfloat16* __restrict__ tw1,
    __hip_bfloat16* __restrict__ o1c,
    float* __restrict__ psum, float* __restrict__ psumsq) {
  __shared__ __hip_bfloat16 Bt[64 * 104];   // 13.3 KB B-tile [hw][c]
  __shared__ __hip_bfloat16 ot[64 * 200];   // 25.6 KB out-tile [hw][ch], pad->2-way max
  const int hwt = blockIdx.x, n = blockIdx.y, mt = blockIdx.z;
  const int t0 = hwt * 64;
  const int tid = threadIdx.x;
  const int lane = tid & 63, w = tid >> 6;

  // stage B: x[c][t0+lane] -> Bt[lane][c] (bf16, row stride 104)
  {
    const float* xp = x + (size_t)n * CIN * HW + t0 + lane;
    const int cb = w * 24;
#pragma unroll
    for (int i6 = 0; i6 < 6; ++i6) {
      const int c0 = cb + i6 * 4;
      float v0 = xp[(size_t)(c0 + 0) * HW];
      float v1 = xp[(size_t)(c0 + 1) * HW];
      float v2 = xp[(size_t)(c0 + 2) * HW];
      float v3 = xp[(size_t)(c0 + 3) * HW];
      unsigned lo = (unsigned)f2b(v0) | ((unsigned)f2b(v1) << 16);
      unsigned hi = (unsigned)f2b(v2) | ((unsigned)f2b(v3) << 16);
      *reinterpret_cast<uint2*>(&Bt[lane * 104 + c0]) = make_uint2(lo, hi);
    }
  }
  __syncthreads();

  const int l15 = lane & 15, lh = lane >> 4;
  f32x4 acc[3][4];
#pragma unroll
  for (int f = 0; f < 3; ++f)
#pragma unroll
    for (int g = 0; g < 4; ++g) acc[f][g] = (f32x4){0.f, 0.f, 0.f, 0.f};
  const int rowb = mt * 192 + w * 48;
#pragma unroll
  for (int k0 = 0; k0 < 3; ++k0) {
    s16x8 a[3], b[4];
#pragma unroll
    for (int f = 0; f < 3; ++f)
      a[f] = *reinterpret_cast<const s16x8*>(tw1 + (size_t)(rowb + f * 16 + l15) * CIN + k0 * 32 + lh * 8);
#pragma unroll
    for (int g = 0; g < 4; ++g)
      b[g] = *reinterpret_cast<const s16x8*>(&Bt[(g * 16 + l15) * 104 + k0 * 32 + lh * 8]);
#pragma unroll
    for (int f = 0; f < 3; ++f)
#pragma unroll
      for (int g = 0; g < 4; ++g)
        acc[f][g] = __builtin_amdgcn_mfma_f32_16x16x32_bf16(a[f], b[g], acc[f][g], 0, 0, 0);
  }

  // BN partials from acc (register-side, width-16 shuffles)
#pragma unroll
  for (int f = 0; f < 3; ++f) {
    float sred[4] = {0.f, 0.f, 0.f, 0.f};
    float qred[4] = {0.f, 0.f, 0.f, 0.f};
    const int ch0 = rowb + f * 16 + lh * 4;
#pragma unroll
    for (int g = 0; g < 4; ++g)
#pragma unroll
      for (int r = 0; r < 4; ++r) {
        float v = acc[f][g][r];
        sred[r] += v; qred[r] = fmaf(v, v, qred[r]);
      }
#pragma unroll
    for (int r = 0; r < 4; ++r) {
      float s = sred[r], q = qred[r];
#pragma unroll
      for (int m = 1; m < 16; m <<= 1) { s += __shfl_xor(s, m); q += __shfl_xor(q, m); }
      if (l15 == 0) {
        const int pi = (ch0 + r) * 1568 + n * NT + hwt;
        psum[pi] = s; psumsq[pi] = q;
      }
    }
  }

  // pass 1: acc -> ot[hw][ch] (uint2 per lane; <=2-way bank aliasing = free)
#pragma unroll
  for (int f = 0; f < 3; ++f) {
    const int chL = w * 48 + f * 16 + lh * 4;
#pragma unroll
    for (int g = 0; g < 4; ++g) {
      unsigned p0 = (unsigned)f2b(acc[f][g][0]) | ((unsigned)f2b(acc[f][g][1]) << 16);
      unsigned p1 = (unsigned)f2b(acc[f][g][2]) | ((unsigned)f2b(acc[f][g][3]) << 16);
      *reinterpret_cast<uint2*>(&ot[(g * 16 + l15) * 200 + chL]) = make_uint2(p0, p1);
    }
  }
  __syncthreads();

  // pass 2: full-sector stores: 4 consecutive lanes cover 64B contiguous channels
  {
    const int hwp = tid >> 2, q = tid & 3;
    const __hip_bfloat16* src = &ot[hwp * 200];
    __hip_bfloat16* dst = o1c + ((size_t)n * HW + t0 + hwp) * PL + mt * 192;
#pragma unroll
    for (int s = 0; s < 6; ++s) {
      const int c8 = q + s * 4;   // 16B chunk index, 24 chunks = 192 ch
      *reinterpret_cast<uint4*>(dst + c8 * 8) =
          *reinterpret_cast<const uint4*>(src + c8 * 8);
    }
  }
}

// ---------------- depthwise 3x3: register rolling window, deep pipeline ---------
// grid (14 col-strips of 4, 9 ch-chunks of 64, 32 batch). block 64 (1 wave).
// lane = col(0..3)*16 + chs(0..15); each lane owns 4 channels of one column.
// 16 consecutive lanes = 64 ch * 2B = one FULL 128B line per column per load.
// 8-slot raw queue (prefetch distance 7 rows) + 4-slot converted window ring.
__global__ __launch_bounds__(64) void dw_kernel(
    const __hip_bfloat16* __restrict__ o1c, const float* __restrict__ tw2,
    const float* __restrict__ s1, const float* __restrict__ t1,
    __hip_bfloat16* __restrict__ o2c,
    float* __restrict__ psum, float* __restrict__ psumsq) {
  const int strip = blockIdx.x, kh = blockIdx.y, n = blockIdx.z;
  const int lane = threadIdx.x;
  const int col = lane >> 4, chs = lane & 15;
  const int c = strip * 4 + col;
  const int chb = kh * 64 + chs * 4;
  const int ec = (col == 0) ? (c - 1) : (c + 1);   // halo column this lane may load
  const bool eok = (col == 0) ? (c > 0) : ((col == 3) ? (c < 55) : false);

  float sc[4], sh[4], wt[9][4];
#pragma unroll
  for (int j = 0; j < 4; ++j) {
    sc[j] = s1[chb + j]; sh[j] = t1[chb + j];
#pragma unroll
    for (int t = 0; t < 9; ++t) wt[t][j] = tw2[(chb + j) * 9 + t];
  }

  const size_t nb = (size_t)n * HW;
  const __hip_bfloat16* pc = o1c + (nb + c) * PL + chb;
  const __hip_bfloat16* pe = o1c + (nb + ((eok ? ec : c))) * PL + chb;
  __hip_bfloat16* po = o2c + (nb + c) * PL + chb;

  uint2 rc[8], re[8];
  float Wl[4][4], Wc[4][4], Wr[4][4];
  float psc[4] = {0.f, 0.f, 0.f, 0.f}, psq[4] = {0.f, 0.f, 0.f, 0.f};

#define LOADRAW(s, q_) do {                                                    \
    rc[s] = make_uint2(0u, 0u); re[s] = make_uint2(0u, 0u);                    \
    if ((q_) < 56) {                                                           \
      rc[s] = *reinterpret_cast<const uint2*>(pc + (size_t)(q_) * 56 * PL);    \
      if (eok) re[s] = *reinterpret_cast<const uint2*>(pe + (size_t)(q_) * 56 * PL); \
    } } while (0)

#define BN4(dst, raw) do {                                                     \
    dst[0] = fmaxf(fmaf(b2f((raw).x), sc[0], sh[0]), 0.f);                     \
    dst[1] = fmaxf(fmaf(b2f((raw).x >> 16), sc[1], sh[1]), 0.f);               \
    dst[2] = fmaxf(fmaf(b2f((raw).y), sc[2], sh[2]), 0.f);                     \
    dst[3] = fmaxf(fmaf(b2f((raw).y >> 16), sc[3], sh[3]), 0.f);               \
  } while (0)

#define CONVW(wi, s, q_) do {                                                  \
    if ((q_) < 56) {                                                           \
      float cen_[4], ee_[4];                                                   \
      BN4(cen_, rc[s]); BN4(ee_, re[s]);                                       \
      _Pragma("unroll")                                                        \
      for (int j = 0; j < 4; ++j) {                                            \
        float lv = __shfl(cen_[j], lane - 16);                                 \
        float rv = __shfl(cen_[j], lane + 16);                                 \
        float ev = eok ? ee_[j] : 0.f;                                         \
        Wc[wi][j] = cen_[j];                                                   \
        Wl[wi][j] = (col == 0) ? ev : lv;                                      \
        Wr[wi][j] = (col == 3) ? ev : rv;                                      \
      }                                                                        \
    } else {                                                                   \
      _Pragma("unroll")                                                        \
      for (int j = 0; j < 4; ++j) { Wl[wi][j] = 0.f; Wc[wi][j] = 0.f; Wr[wi][j] = 0.f; } \
    } } while (0)

#define COMPW(qm, q0, qp, q_) do {                                             \
    float o_[4];                                                               \
    _Pragma("unroll")                                                          \
    for (int j = 0; j < 4; ++j) {                                              \
      float a_ = wt[0][j] * Wl[qm][j];                                         \
      a_ = fmaf(wt[1][j], Wc[qm][j], a_);                                      \
      a_ = fmaf(wt[2][j], Wr[qm][j], a_);                                      \
      a_ = fmaf(wt[3][j], Wl[q0][j], a_);                                      \
      a_ = fmaf(wt[4][j], Wc[q0][j], a_);                                      \
      a_ = fmaf(wt[5][j], Wr[q0][j], a_);                                      \
      a_ = fmaf(wt[6][j], Wl[qp][j], a_);                                      \
      a_ = fmaf(wt[7][j], Wc[qp][j], a_);                                      \
      a_ = fmaf(wt[8][j], Wr[qp][j], a_);                                      \
      o_[j] = a_;                                                              \
      psc[j] += a_; psq[j] = fmaf(a_, a_, psq[j]);                             \
    }                                                                          \
    unsigned pk0 = (unsigned)f2b(o_[0]) | ((unsigned)f2b(o_[1]) << 16);        \
    unsigned pk1 = (unsigned)f2b(o_[2]) | ((unsigned)f2b(o_[3]) << 16);        \
    *reinterpret_cast<uint2*>(po + (size_t)(q_) * 56 * PL) = make_uint2(pk0, pk1); \
  } while (0)

  // prologue: rows 0..7 in flight (16 independent loads); convert row 0;
  // window slot 3 = row -1 = zeros.
  LOADRAW(0, 0); LOADRAW(1, 1); LOADRAW(2, 2); LOADRAW(3, 3);
  LOADRAW(4, 4); LOADRAW(5, 5); LOADRAW(6, 6); LOADRAW(7, 7);
  CONVW(0, 0, 0);
#pragma unroll
  for (int j = 0; j < 4; ++j) { Wl[3][j] = 0.f; Wc[3][j] = 0.f; Wr[3][j] = 0.f; }

  for (int t = 0; t < 7; ++t) {
    const int q = 8 * t;
    LOADRAW(0, q + 8);  CONVW(1, 1, q + 1);  COMPW(3, 0, 1, q);
    LOADRAW(1, q + 9);  CONVW(2, 2, q + 2);  COMPW(0, 1, 2, q + 1);
    LOADRAW(2, q + 10); CONVW(3, 3, q + 3);  COMPW(1, 2, 3, q + 2);
    LOADRAW(3, q + 11); CONVW(0, 4, q + 4);  COMPW(2, 3, 0, q + 3);
    LOADRAW(4, q + 12); CONVW(1, 5, q + 5);  COMPW(3, 0, 1, q + 4);
    LOADRAW(5, q + 13); CONVW(2, 6, q + 6);  COMPW(0, 1, 2, q + 5);
    LOADRAW(6, q + 14); CONVW(3, 7, q + 7);  COMPW(1, 2, 3, q + 6);
    LOADRAW(7, q + 15); CONVW(0, 0, q + 8);  COMPW(2, 3, 0, q + 7);
  }
#undef COMPW
#undef CONVW
#undef BN4
#undef LOADRAW

  // BN2 partials: reduce over the wave's 4 columns (lanes differing in bits 4-5)
#pragma unroll
  for (int j = 0; j < 4; ++j) {
    psc[j] += __shfl_xor(psc[j], 16); psc[j] += __shfl_xor(psc[j], 32);
    psq[j] += __shfl_xor(psq[j], 16); psq[j] += __shfl_xor(psq[j], 32);
  }
  if (col == 0) {
#pragma unroll
    for (int j = 0; j < 4; ++j) {
      const int pi = (chb + j) * 448 + n * 14 + strip;
      psum[pi] = psc[j]; psumsq[pi] = psq[j];
    }
  }
}

// ---------------- conv3: 1x1 project 576->96, staged + XOR-swizzled LDS ---------
// grid (49, 32). block 256 = 4 waves in 2x2 (48 cout x 32 hw each).
// LDS: chunk dbuf (16 KB) ALIASES epilogue bounce (24.96 KB) -> 29.6 KB total
// -> 5 blocks/CU. 2-deep register prefetch (load kc+2 while computing kc).
__global__ __launch_bounds__(256) void conv3_mfma(
    const __hip_bfloat16* __restrict__ o2c, const __hip_bfloat16* __restrict__ tw3,
    const float* __restrict__ s2, const float* __restrict__ t2,
    __hip_bfloat16* __restrict__ out3,
    float* __restrict__ psum, float* __restrict__ psumsq) {
  __shared__ alignas(16) char shraw[96 * 65 * 4];   // 24.96 KB: chunk[2][8KB] ∪ smem f32
  __shared__ float s2s[PL], t2s[PL];
  float* smem = reinterpret_cast<float*>(shraw);
  const int hwt = blockIdx.x, n = blockIdx.y, tid = threadIdx.x;
  const int lane = tid & 63, w = tid >> 6;
  const int l15 = lane & 15, lh = lane >> 4;
  const int wm = w >> 1, wn = w & 1;
  const int t0 = hwt * 64;
  for (int i = tid; i < PL; i += 256) { s2s[i] = s2[i]; t2s[i] = t2[i]; }

  const int hwp = tid >> 2;          // 0..63
  const int cq = tid & 3;            // 16-ch group
  const __hip_bfloat16* src = o2c + ((size_t)n * HW + t0 + hwp) * PL + cq * 16;
  uint4 qa[2], qb[2];
  qa[0] = *reinterpret_cast<const uint4*>(src);
  qb[0] = *reinterpret_cast<const uint4*>(src + 8);
  qa[1] = *reinterpret_cast<const uint4*>(src + 64);
  qb[1] = *reinterpret_cast<const uint4*>(src + 64 + 8);

  f32x4 acc[3][2];
#pragma unroll
  for (int f = 0; f < 3; ++f)
#pragma unroll
    for (int g = 0; g < 2; ++g) acc[f][g] = (f32x4){0.f, 0.f, 0.f, 0.f};

  const unsigned key = (unsigned)((hwp & 7) << 4);
  __syncthreads();   // s2s ready

#pragma unroll
  for (int kc = 0; kc < 9; ++kc) {
    const int pb = kc & 1;
    // BN2+ReLU on prefetched regs, pack, swizzled LDS write into chunk[pb]
    {
      const int cb16 = kc * 64 + cq * 16;
      unsigned uu[8] = {qa[pb].x, qa[pb].y, qa[pb].z, qa[pb].w,
                        qb[pb].x, qb[pb].y, qb[pb].z, qb[pb].w};
      unsigned po[8];
#pragma unroll
      for (int j = 0; j < 8; ++j) {
        float lo = fmaxf(fmaf(b2f(uu[j]),       s2s[cb16 + 2 * j],     t2s[cb16 + 2 * j]), 0.f);
        float hi = fmaxf(fmaf(b2f(uu[j] >> 16), s2s[cb16 + 2 * j + 1], t2s[cb16 + 2 * j + 1]), 0.f);
        po[j] = (unsigned)f2b(lo) | ((unsigned)f2b(hi) << 16);
      }
      char* base = shraw + pb * 8192 + hwp * 128;
      *reinterpret_cast<uint4*>(base + (((unsigned)(cq * 32)) ^ key)) =
          make_uint4(po[0], po[1], po[2], po[3]);
      *reinterpret_cast<uint4*>(base + (((unsigned)(cq * 32 + 16)) ^ key)) =
          make_uint4(po[4], po[5], po[6], po[7]);
    }
    __syncthreads();
    if (kc < 7) {   // prefetch chunk kc+2 into the regs just consumed
      qa[pb] = *reinterpret_cast<const uint4*>(src + (kc + 2) * 64);
      qb[pb] = *reinterpret_cast<const uint4*>(src + (kc + 2) * 64 + 8);
    }
#pragma unroll
    for (int kb = 0; kb < 2; ++kb) {
      s16x8 a[3];
#pragma unroll
      for (int f = 0; f < 3; ++f)
        a[f] = *reinterpret_cast<const s16x8*>(
            tw3 + (size_t)(wm * 48 + f * 16 + l15) * PL + kc * 64 + kb * 32 + lh * 8);
#pragma unroll
      for (int g = 0; g < 2; ++g) {
        const int row = wn * 32 + g * 16 + l15;
        const unsigned cbyte = (unsigned)(kb * 64 + lh * 16) ^ (unsigned)((row & 7) << 4);
        const s16x8 b = *reinterpret_cast<const s16x8*>(
            shraw + pb * 8192 + row * 128 + cbyte);
#pragma unroll
        for (int f = 0; f < 3; ++f)
          acc[f][g] = __builtin_amdgcn_mfma_f32_16x16x32_bf16(a[f], b, acc[f][g], 0, 0, 0);
      }
    }
  }
  __syncthreads();   // last MFMA reads drained; safe to overwrite with smem
#pragma unroll
  for (int f = 0; f < 3; ++f)
#pragma unroll
    for (int g = 0; g < 2; ++g)
#pragma unroll
      for (int r = 0; r < 4; ++r)
        smem[(wm * 48 + f * 16 + lh * 4 + r) * 65 + wn * 32 + g * 16 + l15] = acc[f][g][r];
  __syncthreads();
  const int slot = tid & 7, rgrp = tid >> 3;
#pragma unroll
  for (int s = 0; s < 3; ++s) {
    const int rl = s * 32 + rgrp;
    float v[8], sm = 0.f, sq = 0.f;
#pragma unroll
    for (int j = 0; j < 8; ++j) {
      float t = smem[rl * 65 + slot * 8 + j];
      v[j] = t; sm += t; sq = fmaf(t, t, sq);
    }
    unsigned pk[4];
#pragma unroll
    for (int j = 0; j < 4; ++j) pk[j] = (unsigned)f2b(v[2 * j]) | ((unsigned)f2b(v[2 * j + 1]) << 16);
    *reinterpret_cast<uint4*>(out3 + ((size_t)n * COUT + rl) * HW + t0 + slot * 8) =
        make_uint4(pk[0], pk[1], pk[2], pk[3]);
#pragma unroll
    for (int m = 1; m < 8; m <<= 1) { sm += __shfl_xor(sm, m, 8); sq += __shfl_xor(sq, m, 8); }
    if (slot == 0) { int pi = rl * 1568 + n * NT + hwt; psum[pi] = sm; psumsq[pi] = sq; }
  }
}

// ---------------- final: out = BN3(out3_bf16) + x -------------------------------
__global__ __launch_bounds__(256) void final_kernel(
    const __hip_bfloat16* __restrict__ out3, const float* __restrict__ x,
    const float* __restrict__ s3, const float* __restrict__ t3,
    float* __restrict__ out) {
  const int i = blockIdx.x * 256 + threadIdx.x;   // float4 index, grid exact
  const int p = (i * 4) / HW;
  const int co = p - (p / COUT) * COUT;
  uint2 raw = reinterpret_cast<const uint2*>(out3)[i];
  float4 b = reinterpret_cast<const float4*>(x)[i];
  const float scv = s3[co], tv = t3[co];
  float4 r;
  r.x = fmaf(b2f(raw.x), scv, tv) + b.x;
  r.y = fmaf(b2f(raw.x >> 16), scv, tv) + b.y;
  r.z = fmaf(b2f(raw.y), scv, tv) + b.z;
  r.w = fmaf(b2f(raw.y >> 16), scv, tv) + b.w;
  reinterpret_cast<float4*>(out)[i] = r;
}

extern "C" void kernel_launch(void* const* d_in, const int* in_sizes, int n_in,
                              void* d_out, int out_size, void* d_ws, size_t ws_size,
                              hipStream_t stream) {
  const float* x  = (const float*)d_in[0];
  const float* w1 = (const float*)d_in[1];
  const float* g1 = (const float*)d_in[2];
  const float* b1 = (const float*)d_in[3];
  const float* w2 = (const float*)d_in[4];
  const float* g2 = (const float*)d_in[5];
  const float* b2 = (const float*)d_in[6];
  const float* w3 = (const float*)d_in[7];
  const float* g3 = (const float*)d_in[8];
  const float* b3 = (const float*)d_in[9];
  float* out = (float*)d_out;

  char* ws = (char*)d_ws;
  __hip_bfloat16* tw1b = (__hip_bfloat16*)(ws + 0);            // 110592 B
  __hip_bfloat16* tw3b = (__hip_bfloat16*)(ws + 110592);       // 110592 B
  float* tw2f = (float*)(ws + 221184);                          // 20736 B
  float* s1 = (float*)(ws + 241920);
  float* t1 = s1 + PL; float* s2 = t1 + PL; float* t2 = s2 + PL;
  float* s3 = (float*)(ws + 251136); float* t3 = s3 + COUT;
  float* ps1 = (float*)(ws + 251904);                           // 576*1568 f32
  float* pq1 = ps1 + PL * 1568;
  float* ps2 = pq1 + PL * 1568;                                 // 576*448 used
  float* pq2 = ps2 + PL * 1568;
  float* ps3 = pq2 + PL * 1568;                                 // 96*1568 f32
  float* pq3 = ps3 + COUT * 1568;
  float* part1 = pq3 + COUT * 1568;                              // 32 f32 each
  float* part2 = part1 + 32;
  float* part3 = part2 + 32;
  // o1c at 16 MB; o2c after. out3b ALIASES o1c (o1c dead once dw completes).
  __hip_bfloat16* o1c = (__hip_bfloat16*)(ws + 16777216);                 // 115.6 MB
  __hip_bfloat16* o2c = o1c + (size_t)BATCH * HW * PL;                    // 115.6 MB
  __hip_bfloat16* out3b = o1c;                                            // alias

  // ternarize (parallel 2-stage, deterministic)
  absred_kernel<<<32, 256, 0, stream>>>(w1, part1, 13824);
  absred_kernel<<<32, 256, 0, stream>>>(w2, part2, 1296);
  absred_kernel<<<32, 256, 0, stream>>>(w3, part3, 13824);
  ternw_bf16_kernel<<<54, 256, 0, stream>>>(w1, part1, 1.0f / 55296.0f, tw1b, 13824);
  ternw_f32_kernel <<<6, 256, 0, stream>>>(w2, part2, 1.0f / 5184.0f, tw2f, 1296);
  ternw_bf16_kernel<<<54, 256, 0, stream>>>(w3, part3, 1.0f / 55296.0f, tw3b, 13824);

  conv1_mfma<<<dim3(NT, BATCH, 3), 256, 0, stream>>>(x, tw1b, o1c, ps1, pq1);
  bnp_kernel<<<PL, 256, 0, stream>>>(ps1, pq1, g1, b1, s1, t1, 1568);

  dw_kernel<<<dim3(14, 9, BATCH), 64, 0, stream>>>(o1c, tw2f, s1, t1, o2c, ps2, pq2);
  bnp_kernel<<<PL, 256, 0, stream>>>(ps2, pq2, g2, b2, s2, t2, 448);

  conv3_mfma<<<dim3(NT, BATCH), 256, 0, stream>>>(o2c, tw3b, s2, t2, out3b, ps3, pq3);
  bnp_kernel<<<COUT, 256, 0, stream>>>(ps3, pq3, g3, b3, s3, t3, 1568);

  final_kernel<<<out_size / 1024, 256, 0, stream>>>(out3b, x, s3, t3, out);
}